// Round 7
// baseline (180.793 us; speedup 1.0000x reference)
//
#include <hip/hip_runtime.h>
#include <hip/hip_fp16.h>

static constexpr int Hh = 384;
static constexpr int Ww = 1280;
static constexpr int HW = Hh * Ww;            // 491520
static constexpr int TILE_I = 32;             // output tile rows
static constexpr int TILE_J = 40;             // output tile cols
static constexpr int T = 24;                  // ALL steps fused, single launch
static constexpr int RI = TILE_I + 2 * T;     // 80: region rows incl. halo
static constexpr int RJ = TILE_J + 2 * T;     // 88: region cols incl. halo
static constexpr int RR = RI * RJ;            // 7040
static constexpr int II = RI - 2;             // 78: interior rows
static constexpr int IJ = RJ - 2;             // 86: interior cols
static constexpr int NINT = II * IJ;          // 6708 interior pixels
static constexpr int BLOCK = 512;
static constexpr int PPQ = (RR + BLOCK - 1) / BLOCK;    // 14 region px / thread
static constexpr int PPI = (NINT + BLOCK - 1) / BLOCK;  // 14 interior px / thread
static constexpr int TI = Hh / TILE_I;        // 12
static constexpr int TJ = Ww / TILE_J;        // 32
static constexpr int GRID = 2 * TI * TJ;      // 768 = exactly 3 blocks/CU
static constexpr int NXCD = 8;
static constexpr int CHUNK = GRID / NXCD;     // 96 (768 % 8 == 0 -> bijective)
static constexpr float EPSF = 1e-9f;

// k order matches reference PADS: (di,dj) =
// k:   0       1       2       3       4       5       6       7
//    (+1,+1) (+1,0) (+1,-1) (0,+1) (0,-1) (-1,+1) (-1,0) (-1,-1)
static constexpr int DI[8] = { 1, 1, 1, 0, 0, -1, -1, -1 };
static constexpr int DJ[8] = { 1, 0, -1, 1, -1, 1, 0, -1 };

static __device__ __forceinline__ int iclamp(int v, int lo, int hi) {
    return min(max(v, lo), hi);
}

// Single launch, zero inter-block communication: each block owns a 32x40
// output tile and carries the full 24-step halo (80x88 region) in LDS.
//
// Round-7: re-tiled for the MEASURED register budget. Knob ledger across
// rounds 3-6: (512,2)->128 VGPR; (1024,4)->64; (1024)+waves_per_eu(4,4)->64
// (attr ignored); (1024,1)->64. Only 512-thread blocks with (512,2) ever
// yielded a 128-VGPR budget; 1024-thread blocks are pinned at 64 no matter
// what. So: BLOCK=512 + (512,2), and shrink per-thread state to fit 128:
//   PPI=14 -> wh 56 + Cc 14 + pr 14 = 84 persistent, ~110 peak < 128.
// LDS 2x7040x4 = 55 KB -> 2 blocks/CU co-resident (16 waves/CU = 4/SIMD x
// 128 VGPR = exactly the full register file). Grid 768 = exactly 3
// blocks/CU, zero tail imbalance. Trade: 1.5x more redundant halo compute
// than the 64x64 tiling, in exchange for eliminating ~75 MB of scratch
// spill (round-6 WRITE_SIZE 79 MB vs 4 MB ideal) and doubling occupancy.
//
//  - d ping-pongs in LDS; neighbor offsets are compile-time immediates
//    (row stride RJ=88) so each tap is one ds_read_b32 off base p.
//  - Weights computed inline from guidance (normalization + sparse clamp
//    baked in), packed fp16 in registers for all 24 steps.
//  - Shrinking active set: step s computes only pixels with ring >= s
//    (ring-r values are consumed only through step r+1); step 24's active
//    set is exactly the valid 32x40 center.
//  - Ring-0 staged once into sd[0]; induction: step s reads rings >= s-1
//    from the buffer written at step s-1, so stale entries are never read.
//  - Out-of-image region pixels hold clamped duplicates; they never reach
//    the center because image-boundary pixels have weight 0 toward
//    out-of-bounds neighbors (zero-padded guidance).
//  - s-loop NOT unrolled (I-cache); q-loops unrolled so arrays stay in regs.
__global__ __launch_bounds__(BLOCK, 2)
void mega(
    const float* __restrict__ g,
    const float* __restrict__ blur,
    const float* __restrict__ sparse,
    float* __restrict__ out)
{
    __shared__ float sd[2][RR];

    const int tid = threadIdx.x;
    // XCD-aware bijective swizzle: consecutive tiles (which share halo
    // guidance/blur reads) land on the same XCD's private L2.
    int bx = ((int)blockIdx.x % NXCD) * CHUNK + (int)blockIdx.x / NXCD;
    const int tj = bx % TJ; bx /= TJ;
    const int ti = bx % TI;
    const int b  = bx / TI;
    const int oi = ti * TILE_I - T;        // region origin (image coords)
    const int oj = tj * TILE_J - T;

    const float* blurb = blur + (size_t)b * HW;
    const float* gb    = g    + (size_t)b * 8 * HW;

    // --- stage d0 = blur over the whole region (image-clamped) ---
#pragma unroll
    for (int q = 0; q < PPQ; q++) {
        int p = tid + q * BLOCK;
        if (p < RR) {
            int ri = p / RJ, rj = p - ri * RJ;
            int gi = iclamp(oi + ri, 0, Hh - 1);
            int gj = iclamp(oj + rj, 0, Ww - 1);
            sd[0][p] = blurb[gi * Ww + gj];
        }
    }

    // --- weights (packed fp16) + C for interior pixels; registers for all
    // 24 steps. pr packed: low 16 = region offset, high 16 = ring dist ---
    __half2 wh[PPI][4];
    float   Cc[PPI];
    int     pr[PPI];
#pragma unroll
    for (int q = 0; q < PPI; q++) {
        int pi = tid + q * BLOCK;
        if (pi < NINT) {
            int r0 = pi / IJ;
            int ri = 1 + r0, rj = 1 + (pi - r0 * IJ);
            int rng = min(min(ri, RI - 1 - ri), min(rj, RJ - 1 - rj));
            pr[q] = (ri * RJ + rj) | (rng << 16);
            int gi = iclamp(oi + ri, 0, Hh - 1);
            int gj = iclamp(oj + rj, 0, Ww - 1);
            float v[8];
            float a = EPSF;
#pragma unroll
            for (int k = 0; k < 8; k++) {
                int ii = gi + DI[k], jj = gj + DJ[k];
                float gv = 0.0f;
                if (ii >= 0 && ii < Hh && jj >= 0 && jj < Ww)
                    gv = gb[k * HW + ii * Ww + jj];
                v[k] = gv;
                a += fabsf(gv);
            }
            float inv = 1.0f / a, gs = 0.0f;
#pragma unroll
            for (int k = 0; k < 8; k++) { v[k] *= inv; gs += v[k]; }
            int idx = gi * Ww + gj;
            float rawv = blurb[idx];
            bool m = sparse[b * HW + idx] > 0.0f;  // sparse>=0; sign(s)==1 iff s>0
            Cc[q] = m ? rawv : (1.0f - gs) * rawv;
#pragma unroll
            for (int k = 0; k < 4; k++) {
                __half2 h;
                h.x = __float2half(m ? 0.0f : v[2 * k]);
                h.y = __float2half(m ? 0.0f : v[2 * k + 1]);
                wh[q][k] = h;
            }
        } else {
            pr[q] = 0; Cc[q] = 0.0f;
#pragma unroll
            for (int k = 0; k < 4; k++) wh[q][k] = __floats2half2_rn(0.0f, 0.0f);
        }
    }
    __syncthreads();

    // --- steps 1..T-1 in LDS; step s touches only ring >= s ---
    int cur = 0;
#pragma unroll 1
    for (int s = 1; s < T; ++s) {
        const float* s0 = sd[cur];
        float* s1 = sd[cur ^ 1];
#pragma unroll
        for (int q = 0; q < PPI; q++) {
            if ((pr[q] >> 16) >= s) {
                int p = pr[q] & 0xffff;
                float2 w01 = __half22float2(wh[q][0]);
                float2 w23 = __half22float2(wh[q][1]);
                float2 w45 = __half22float2(wh[q][2]);
                float2 w67 = __half22float2(wh[q][3]);
                float v = Cc[q]
                    + w01.x * s0[p + RJ + 1] + w01.y * s0[p + RJ]
                    + w23.x * s0[p + RJ - 1] + w23.y * s0[p + 1]
                    + w45.x * s0[p - 1]      + w45.y * s0[p - RJ + 1]
                    + w67.x * s0[p - RJ]     + w67.y * s0[p - RJ - 1];
                s1[p] = v;
            }
        }
        __syncthreads();
        cur ^= 1;
    }

    // --- step T: ring >= T is exactly the valid 32x40 center; write out ---
    const float* s0 = sd[cur];
#pragma unroll
    for (int q = 0; q < PPI; q++) {
        if ((pr[q] >> 16) >= T) {
            int p = pr[q] & 0xffff;
            float2 w01 = __half22float2(wh[q][0]);
            float2 w23 = __half22float2(wh[q][1]);
            float2 w45 = __half22float2(wh[q][2]);
            float2 w67 = __half22float2(wh[q][3]);
            float v = Cc[q]
                + w01.x * s0[p + RJ + 1] + w01.y * s0[p + RJ]
                + w23.x * s0[p + RJ - 1] + w23.y * s0[p + 1]
                + w45.x * s0[p - 1]      + w45.y * s0[p - RJ + 1]
                + w67.x * s0[p - RJ]     + w67.y * s0[p - RJ - 1];
            int ri = p / RJ, rj = p - ri * RJ;
            out[b * HW + (oi + ri) * Ww + (oj + rj)] = v;
        }
    }
}

extern "C" void kernel_launch(void* const* d_in, const int* in_sizes, int n_in,
                              void* d_out, int out_size, void* d_ws, size_t ws_size,
                              hipStream_t stream) {
    const float* guidance = (const float*)d_in[0];
    const float* blur     = (const float*)d_in[1];
    const float* sparse   = (const float*)d_in[2];
    float* out = (float*)d_out;

    mega<<<GRID, BLOCK, 0, stream>>>(guidance, blur, sparse, out);
}

// Round 8
// 172.680 us; speedup vs baseline: 1.0470x; 1.0470x over previous
//
#include <hip/hip_runtime.h>
#include <hip/hip_fp16.h>

static constexpr int Hh = 384;
static constexpr int Ww = 1280;
static constexpr int HW = Hh * Ww;            // 491520
static constexpr int TILE_I = 32;             // output tile rows
static constexpr int TILE_J = 40;             // output tile cols
static constexpr int T = 24;                  // ALL steps fused, single launch
static constexpr int RI = TILE_I + 2 * T;     // 80: region rows incl. halo
static constexpr int RJ = TILE_J + 2 * T;     // 88: region cols incl. halo
static constexpr int RR = RI * RJ;            // 7040
static constexpr int II = RI - 2;             // 78: interior rows
static constexpr int IJ = RJ - 2;             // 86: interior cols
static constexpr int NPAIR_ROW = IJ / 2;      // 43 pairs per interior row (exact)
static constexpr int NPAIR = II * NPAIR_ROW;  // 3354 pairs
static constexpr int BLOCK = 512;
static constexpr int PPQ = (RR + BLOCK - 1) / BLOCK;      // 14 region px / thread
static constexpr int PPR = (NPAIR + BLOCK - 1) / BLOCK;   // 7 pairs / thread
static constexpr int TI = Hh / TILE_I;        // 12
static constexpr int TJ = Ww / TILE_J;        // 32
static constexpr int GRID = 2 * TI * TJ;      // 768 = exactly 3 blocks/CU
static constexpr int NXCD = 8;
static constexpr int CHUNK = GRID / NXCD;     // 96 (768 % 8 == 0 -> bijective)
static constexpr float EPSF = 1e-9f;

// k order matches reference PADS: (di,dj) =
// k:   0       1       2       3       4       5       6       7
//    (+1,+1) (+1,0) (+1,-1) (0,+1) (0,-1) (-1,+1) (-1,0) (-1,-1)
static constexpr int DI[8] = { 1, 1, 1, 0, 0, -1, -1, -1 };
static constexpr int DJ[8] = { 1, 0, -1, 1, -1, 1, 0, -1 };

static __device__ __forceinline__ int iclamp(int v, int lo, int hi) {
    return min(max(v, lo), hi);
}

// Single launch, zero inter-block communication: each block owns a 32x40
// output tile and carries the full 24-step halo (80x88 region) in LDS.
//
// Round-8: pixel-PAIR processing. Round-7 counters (no spill, VGPR 96,
// WRITE 3.8 MB, dur 120us, VALUBusy 44%) imply the LDS pipe is the
// bottleneck: 8x ds_read_b32 + 1 write per px-step = ~215k LDS cycles/CU
// = ~89us of the 120. Fix: each lane owns 7 HORIZONTAL PAIRS (same 14 px).
// A pair's 8-tap stencil needs 12 distinct values = 6 ds_read_b64 (pairs
// start at odd region col -> all +-RJ+-1 bases even -> 8B aligned) vs 16
// b32 reads; write merges to one ds_write2_b32. Weights packed
// half2(w_k[px0], w_k[px1]); fmaf(__low2float(w), d, acc) is the
// v_fma_mix_f32 pattern (worst case = same cvt count as round 7).
// Interior 78x86 -> exactly 43 pairs/row, pairs never wrap rows.
//
//  - Shrinking active set, pair-granular: compute pair if max(ring0,ring1)
//    >= s. A partner px below the cutoff computes from possibly-stale but
//    BOUNDED values and its output is never read by any in-cutoff pixel
//    at a later step (step s+1 reads only ring >= s). Final step does
//    exact per-px center checks before writing to global.
//  - Ring-0 staged once into sd[0]; all interior px have ring >= 1, so
//    step 1 is garbage-free and induction holds.
//  - Out-of-image region px hold clamped duplicates; never reach the
//    center (boundary px have weight 0 toward out-of-bounds neighbors).
//  - Knob ledger (r3-r6): only BLOCK=512 + __launch_bounds__(512,2) gives
//    the 128-VGPR budget; 1024-thread blocks are pinned at 64. Persistent
//    state here: wp 56 + Cc 14 + pr 7 = 77 regs -> no spill.
//  - s-loop NOT unrolled (I-cache); q-loops unrolled so arrays stay in regs.
__global__ __launch_bounds__(BLOCK, 2)
void mega(
    const float* __restrict__ g,
    const float* __restrict__ blur,
    const float* __restrict__ sparse,
    float* __restrict__ out)
{
    __shared__ float sd[2][RR];

    const int tid = threadIdx.x;
    // XCD-aware bijective swizzle: consecutive tiles (which share halo
    // guidance/blur reads) land on the same XCD's private L2.
    int bx = ((int)blockIdx.x % NXCD) * CHUNK + (int)blockIdx.x / NXCD;
    const int tj = bx % TJ; bx /= TJ;
    const int ti = bx % TI;
    const int b  = bx / TI;
    const int oi = ti * TILE_I - T;        // region origin (image coords)
    const int oj = tj * TILE_J - T;

    const float* blurb = blur + (size_t)b * HW;
    const float* gb    = g    + (size_t)b * 8 * HW;

    // --- stage d0 = blur over the whole region (image-clamped) ---
#pragma unroll
    for (int q = 0; q < PPQ; q++) {
        int p = tid + q * BLOCK;
        if (p < RR) {
            int ri = p / RJ, rj = p - ri * RJ;
            int gi = iclamp(oi + ri, 0, Hh - 1);
            int gj = iclamp(oj + rj, 0, Ww - 1);
            sd[0][p] = blurb[gi * Ww + gj];
        }
    }

    // --- weights + C per PAIR; registers for all 24 steps.
    // wp[q][k] = half2( w_k[px0], w_k[px1] ); Cc[q] = (C0, C1);
    // pr[q] = region offset of px0 (low 16) | max(ring0,ring1) << 16 ---
    __half2 wp[PPR][8];
    float2  Cc[PPR];
    int     pr[PPR];
#pragma unroll
    for (int q = 0; q < PPR; q++) {
        int pi = tid + q * BLOCK;
        if (pi < NPAIR) {
            int r0 = pi / NPAIR_ROW;
            int c0 = pi - r0 * NPAIR_ROW;
            int ri = 1 + r0;
            int rj = 1 + 2 * c0;           // odd -> all 6 b64 bases aligned
            int p  = ri * RJ + rj;
            int rngr = min(ri, RI - 1 - ri);
            int rng0 = min(rngr, min(rj,     RJ - 1 - rj));
            int rng1 = min(rngr, min(rj + 1, RJ - 2 - rj));
            pr[q] = p | (max(rng0, rng1) << 16);
            float Cv[2], wv[2][8];
#pragma unroll
            for (int x = 0; x < 2; x++) {
                int gi = iclamp(oi + ri, 0, Hh - 1);
                int gj = iclamp(oj + rj + x, 0, Ww - 1);
                float v[8];
                float a = EPSF;
#pragma unroll
                for (int k = 0; k < 8; k++) {
                    int ii = gi + DI[k], jj = gj + DJ[k];
                    float gv = 0.0f;
                    if (ii >= 0 && ii < Hh && jj >= 0 && jj < Ww)
                        gv = gb[k * HW + ii * Ww + jj];
                    v[k] = gv;
                    a += fabsf(gv);
                }
                float inv = 1.0f / a, gs = 0.0f;
#pragma unroll
                for (int k = 0; k < 8; k++) { v[k] *= inv; gs += v[k]; }
                int idx = gi * Ww + gj;
                float rawv = blurb[idx];
                bool m = sparse[b * HW + idx] > 0.0f; // sparse>=0; sign(s)==1 iff s>0
                Cv[x] = m ? rawv : (1.0f - gs) * rawv;
#pragma unroll
                for (int k = 0; k < 8; k++) wv[x][k] = m ? 0.0f : v[k];
            }
            Cc[q] = make_float2(Cv[0], Cv[1]);
#pragma unroll
            for (int k = 0; k < 8; k++)
                wp[q][k] = __halves2half2(__float2half(wv[0][k]),
                                          __float2half(wv[1][k]));
        } else {
            pr[q] = 0; Cc[q] = make_float2(0.0f, 0.0f);
#pragma unroll
            for (int k = 0; k < 8; k++)
                wp[q][k] = __halves2half2(__float2half(0.0f), __float2half(0.0f));
        }
    }
    __syncthreads();

    // --- steps 1..T-1 in LDS; step s touches only pairs with maxring >= s ---
    int cur = 0;
#pragma unroll 1
    for (int s = 1; s < T; ++s) {
        const float* s0 = sd[cur];
        float* s1 = sd[cur ^ 1];
#pragma unroll
        for (int q = 0; q < PPR; q++) {
            if ((pr[q] >> 16) >= s) {
                int p = pr[q] & 0xffff;
                // 12 distinct taps as 6 aligned b64 loads (px0 at col j, px1 at j+1)
                float2 uA = *(const float2*)(s0 + p - RJ - 1);   // (i-1: j-1, j)
                float2 uB = *(const float2*)(s0 + p - RJ + 1);   // (i-1: j+1, j+2)
                float2 mA = *(const float2*)(s0 + p - 1);        // (i  : j-1, j)
                float2 mB = *(const float2*)(s0 + p + 1);        // (i  : j+1, j+2)
                float2 dA = *(const float2*)(s0 + p + RJ - 1);   // (i+1: j-1, j)
                float2 dB = *(const float2*)(s0 + p + RJ + 1);   // (i+1: j+1, j+2)
                float ax = Cc[q].x, ay = Cc[q].y;
                ax = fmaf(__low2float (wp[q][0]), dB.x, ax);
                ay = fmaf(__high2float(wp[q][0]), dB.y, ay);
                ax = fmaf(__low2float (wp[q][1]), dA.y, ax);
                ay = fmaf(__high2float(wp[q][1]), dB.x, ay);
                ax = fmaf(__low2float (wp[q][2]), dA.x, ax);
                ay = fmaf(__high2float(wp[q][2]), dA.y, ay);
                ax = fmaf(__low2float (wp[q][3]), mB.x, ax);
                ay = fmaf(__high2float(wp[q][3]), mB.y, ay);
                ax = fmaf(__low2float (wp[q][4]), mA.x, ax);
                ay = fmaf(__high2float(wp[q][4]), mA.y, ay);
                ax = fmaf(__low2float (wp[q][5]), uB.x, ax);
                ay = fmaf(__high2float(wp[q][5]), uB.y, ay);
                ax = fmaf(__low2float (wp[q][6]), uA.y, ax);
                ay = fmaf(__high2float(wp[q][6]), uB.x, ay);
                ax = fmaf(__low2float (wp[q][7]), uA.x, ax);
                ay = fmaf(__high2float(wp[q][7]), uA.y, ay);
                s1[p]     = ax;
                s1[p + 1] = ay;
            }
        }
        __syncthreads();
        cur ^= 1;
    }

    // --- step T: per-px center checks, write straight to global ---
    const float* s0 = sd[cur];
#pragma unroll
    for (int q = 0; q < PPR; q++) {
        if ((pr[q] >> 16) >= T) {
            int p = pr[q] & 0xffff;
            float2 uA = *(const float2*)(s0 + p - RJ - 1);
            float2 uB = *(const float2*)(s0 + p - RJ + 1);
            float2 mA = *(const float2*)(s0 + p - 1);
            float2 mB = *(const float2*)(s0 + p + 1);
            float2 dA = *(const float2*)(s0 + p + RJ - 1);
            float2 dB = *(const float2*)(s0 + p + RJ + 1);
            float ax = Cc[q].x, ay = Cc[q].y;
            ax = fmaf(__low2float (wp[q][0]), dB.x, ax);
            ay = fmaf(__high2float(wp[q][0]), dB.y, ay);
            ax = fmaf(__low2float (wp[q][1]), dA.y, ax);
            ay = fmaf(__high2float(wp[q][1]), dB.x, ay);
            ax = fmaf(__low2float (wp[q][2]), dA.x, ax);
            ay = fmaf(__high2float(wp[q][2]), dA.y, ay);
            ax = fmaf(__low2float (wp[q][3]), mB.x, ax);
            ay = fmaf(__high2float(wp[q][3]), mB.y, ay);
            ax = fmaf(__low2float (wp[q][4]), mA.x, ax);
            ay = fmaf(__high2float(wp[q][4]), mA.y, ay);
            ax = fmaf(__low2float (wp[q][5]), uB.x, ax);
            ay = fmaf(__high2float(wp[q][5]), uB.y, ay);
            ax = fmaf(__low2float (wp[q][6]), uA.y, ax);
            ay = fmaf(__high2float(wp[q][6]), uB.x, ay);
            ax = fmaf(__low2float (wp[q][7]), uA.x, ax);
            ay = fmaf(__high2float(wp[q][7]), uA.y, ay);
            int ri = p / RJ, rj = p - ri * RJ;
            // maxring >= T guarantees ri in [T, RI-T); cols checked per px.
            int gbase = b * HW + (oi + ri) * Ww + (oj + rj);
            if (rj >= T && rj < RJ - T)         out[gbase]     = ax;
            if (rj + 1 >= T && rj + 1 < RJ - T) out[gbase + 1] = ay;
        }
    }
}

extern "C" void kernel_launch(void* const* d_in, const int* in_sizes, int n_in,
                              void* d_out, int out_size, void* d_ws, size_t ws_size,
                              hipStream_t stream) {
    const float* guidance = (const float*)d_in[0];
    const float* blur     = (const float*)d_in[1];
    const float* sparse   = (const float*)d_in[2];
    float* out = (float*)d_out;

    mega<<<GRID, BLOCK, 0, stream>>>(guidance, blur, sparse, out);
}

// Round 11
// 140.027 us; speedup vs baseline: 1.2911x; 1.2332x over previous
//
#include <hip/hip_runtime.h>

static constexpr int Hh = 384;
static constexpr int Ww = 1280;
static constexpr int HW = Hh * Ww;            // 491520
static constexpr int NPIX = 2 * HW;
static constexpr int TILE_I = 48;             // output tile rows
static constexpr int TILE_J = 40;             // output tile cols
static constexpr int S_STEPS = 8;             // steps per launch; 24 = 3 x 8
static constexpr int RI = TILE_I + 2 * S_STEPS;   // 64
static constexpr int RJ = TILE_J + 2 * S_STEPS;   // 56
static constexpr int RR = RI * RJ;            // 3584
static constexpr int II = RI - 2;             // 62 interior rows
static constexpr int IJ = RJ - 2;             // 54 interior cols
static constexpr int NPAIR_ROW = IJ / 2;      // 27 pairs/row (exact)
static constexpr int NPAIR = II * NPAIR_ROW;  // 1674 pairs
static constexpr int BLOCK = 512;
static constexpr int PPQ = RR / BLOCK;        // 7 region px / thread (exact)
static constexpr int PPR = (NPAIR + BLOCK - 1) / BLOCK;   // 4 pairs / thread
static constexpr int TI_T = Hh / TILE_I;      // 8
static constexpr int TJ_T = Ww / TILE_J;      // 32
static constexpr int GRID = 2 * TI_T * TJ_T;  // 512 = exactly 2 blocks/CU
static constexpr int NXCD = 8;
static constexpr int CHUNK = GRID / NXCD;     // 64 (512 % 8 == 0 -> bijective)
static constexpr float EPSF = 1e-9f;

// k order matches reference PADS: (di,dj) =
// k:   0       1       2       3       4       5       6       7
//    (+1,+1) (+1,0) (+1,-1) (0,+1) (0,-1) (-1,+1) (-1,0) (-1,-1)
static constexpr int DI[8] = { 1, 1, 1, 0, 0, -1, -1, -1 };
static constexpr int DJ[8] = { 1, 0, -1, 1, -1, 1, 0, -1 };

static __device__ __forceinline__ int iclamp(int v, int lo, int hi) {
    return min(max(v, lo), hi);
}

// Round-11 (round-9 design, defensive resubmit after 2x container failure):
// 3 launches x 8 fused steps (halo 8), tile 48x40, pair inner loop.
// Changes vs round-9 source: blur/din are NOT __restrict__ anymore (launch 1
// passed the same pointer for both -> formal restrict-aliasing UB, the only
// real defect found in audit), and launch 1 uses FIRST=true to stage d0
// from blur directly instead of aliasing the parameters.
//
// Why this design (from round-8 counters): the T=24 single launch ran at
// serial LDS+VALU rates (VALUBusy 39%, LDS ~45%, occupancy 22%): 23
// barrier-locked phases leave nothing to overlap, and the deep halo does
// 2.86x redundant px-steps. Splitting 24 = 3x8 cuts px-step work to 0.47x
// (Sum_{s=1..8}(64-2s)(56-2s) = 20848 per block vs minimal 15360 -> 1.36x)
// at the cost of 2 extra launches and 3.9 MB/launch L2-resident d traffic.
//
// Config locked to the measured-good point: BLOCK=512 + __launch_bounds__
// (512,2) is the ONLY incantation that yields a 128-VGPR budget (knob
// ledger r3-r6: (1024,*) and waves_per_eu are pinned/ignored at 64).
// Grid 512 = exactly 2 blocks/CU resident (LDS 28 KB x 2 = 56 KB).
// PPR=4 -> fp32 pair weights fit: 64 (wp) + 8 (Cc) + 4 (pr) = 76
// persistent + ~25 temps < 128 -> no spill; zero fp16 cvt in the inner
// loop: 6 aligned ds_read_b64 + 16 v_fmac_f32 + 2 ds_write_b32.
//
//  - Pairs start at odd region col -> all +-RJ+-1 tap bases even -> 8B
//    aligned (RJ=56 even preserves parity across rows).
//  - Shrinking active set, pair-granular (verified r8): compute pair if
//    max(ring0,ring1) >= s; partner px below cutoff computes bounded
//    stale values never read by in-cutoff px later. Final step does
//    exact per-px center checks.
//  - Out-of-image region px hold clamped duplicates; never reach the
//    center (image-boundary px have weight 0 toward OOB neighbors,
//    from the reference's zero-padded guidance).
//  - C = m ? raw : (1-gate_sum)*raw always from the ORIGINAL blur (raw),
//    recomputed identically each launch; din is the iterate.
template <bool FIRST>
__global__ __launch_bounds__(BLOCK, 2)
void mega(
    const float* __restrict__ g,
    const float* blur,
    const float* __restrict__ sparse,
    const float* din,
    float* __restrict__ dout)
{
    __shared__ float sd[2][RR];

    const int tid = threadIdx.x;
    // XCD-aware bijective swizzle (512 = 8*64): neighbor tiles share halo
    // reads within one XCD's private L2.
    int bx = ((int)blockIdx.x % NXCD) * CHUNK + (int)blockIdx.x / NXCD;
    const int tj = bx % TJ_T; bx /= TJ_T;
    const int ti = bx % TI_T;
    const int b  = bx / TI_T;
    const int oi = ti * TILE_I - S_STEPS;  // region origin (image coords)
    const int oj = tj * TILE_J - S_STEPS;

    const float* blurb = blur + (size_t)b * HW;
    const float* dinb  = (FIRST ? blur : din) + (size_t)b * HW;
    const float* gb    = g + (size_t)b * 8 * HW;

    // --- stage d0 over the whole region (image-clamped; 7x512 exact) ---
#pragma unroll
    for (int q = 0; q < PPQ; q++) {
        int p = tid + q * BLOCK;
        int ri = p / RJ, rj = p - ri * RJ;
        int gi = iclamp(oi + ri, 0, Hh - 1);
        int gj = iclamp(oj + rj, 0, Ww - 1);
        sd[0][p] = dinb[gi * Ww + gj];
    }

    // --- fp32 weights + C per PAIR; registers for all 8 steps.
    // wp[q][k] = (w_k[px0], w_k[px1]); Cc[q] = (C0, C1);
    // pr[q] = region offset of px0 (low 16) | max(ring0,ring1) << 16 ---
    float2 wp[PPR][8];
    float2 Cc[PPR];
    int    pr[PPR];
#pragma unroll
    for (int q = 0; q < PPR; q++) {
        int pi = tid + q * BLOCK;
        if (pi < NPAIR) {
            int r0 = pi / NPAIR_ROW;
            int c0 = pi - r0 * NPAIR_ROW;
            int ri = 1 + r0;
            int rj = 1 + 2 * c0;           // odd -> aligned b64 tap bases
            int p  = ri * RJ + rj;
            int rngr = min(ri, RI - 1 - ri);
            int rng0 = min(rngr, min(rj,     RJ - 1 - rj));
            int rng1 = min(rngr, min(rj + 1, RJ - 2 - rj));
            pr[q] = p | (max(rng0, rng1) << 16);
            float Cv[2], wv[2][8];
#pragma unroll
            for (int x = 0; x < 2; x++) {
                int gi = iclamp(oi + ri, 0, Hh - 1);
                int gj = iclamp(oj + rj + x, 0, Ww - 1);
                float v[8];
                float a = EPSF;
#pragma unroll
                for (int k = 0; k < 8; k++) {
                    int ii = gi + DI[k], jj = gj + DJ[k];
                    float gv = 0.0f;
                    if (ii >= 0 && ii < Hh && jj >= 0 && jj < Ww)
                        gv = gb[k * HW + ii * Ww + jj];
                    v[k] = gv;
                    a += fabsf(gv);
                }
                float inv = 1.0f / a, gs = 0.0f;
#pragma unroll
                for (int k = 0; k < 8; k++) { v[k] *= inv; gs += v[k]; }
                int idx = gi * Ww + gj;
                float rawv = blurb[idx];
                bool m = sparse[b * HW + idx] > 0.0f; // sparse>=0; sign==1 iff >0
                Cv[x] = m ? rawv : (1.0f - gs) * rawv;
#pragma unroll
                for (int k = 0; k < 8; k++) wv[x][k] = m ? 0.0f : v[k];
            }
            Cc[q] = make_float2(Cv[0], Cv[1]);
#pragma unroll
            for (int k = 0; k < 8; k++)
                wp[q][k] = make_float2(wv[0][k], wv[1][k]);
        } else {
            pr[q] = 0;                      // ring 0 -> never active
            Cc[q] = make_float2(0.0f, 0.0f);
#pragma unroll
            for (int k = 0; k < 8; k++) wp[q][k] = make_float2(0.0f, 0.0f);
        }
    }
    __syncthreads();

    // --- steps 1..7 in LDS; step s touches only pairs with maxring >= s ---
    int cur = 0;
#pragma unroll 1
    for (int s = 1; s < S_STEPS; ++s) {
        const float* s0 = sd[cur];
        float* s1 = sd[cur ^ 1];
#pragma unroll
        for (int q = 0; q < PPR; q++) {
            if ((pr[q] >> 16) >= s) {
                int p = pr[q] & 0xffff;
                // 12 distinct taps as 6 aligned b64 loads
                float2 uA = *(const float2*)(s0 + p - RJ - 1);   // (i-1: j-1, j)
                float2 uB = *(const float2*)(s0 + p - RJ + 1);   // (i-1: j+1, j+2)
                float2 mA = *(const float2*)(s0 + p - 1);        // (i  : j-1, j)
                float2 mB = *(const float2*)(s0 + p + 1);        // (i  : j+1, j+2)
                float2 dA = *(const float2*)(s0 + p + RJ - 1);   // (i+1: j-1, j)
                float2 dB = *(const float2*)(s0 + p + RJ + 1);   // (i+1: j+1, j+2)
                float ax = Cc[q].x, ay = Cc[q].y;
                ax = fmaf(wp[q][0].x, dB.x, ax);  ay = fmaf(wp[q][0].y, dB.y, ay);
                ax = fmaf(wp[q][1].x, dA.y, ax);  ay = fmaf(wp[q][1].y, dB.x, ay);
                ax = fmaf(wp[q][2].x, dA.x, ax);  ay = fmaf(wp[q][2].y, dA.y, ay);
                ax = fmaf(wp[q][3].x, mB.x, ax);  ay = fmaf(wp[q][3].y, mB.y, ay);
                ax = fmaf(wp[q][4].x, mA.x, ax);  ay = fmaf(wp[q][4].y, mA.y, ay);
                ax = fmaf(wp[q][5].x, uB.x, ax);  ay = fmaf(wp[q][5].y, uB.y, ay);
                ax = fmaf(wp[q][6].x, uA.y, ax);  ay = fmaf(wp[q][6].y, uB.x, ay);
                ax = fmaf(wp[q][7].x, uA.x, ax);  ay = fmaf(wp[q][7].y, uA.y, ay);
                s1[p]     = ax;
                s1[p + 1] = ay;
            }
        }
        __syncthreads();
        cur ^= 1;
    }

    // --- step 8: per-px center checks, write straight to global ---
    const float* s0 = sd[cur];
#pragma unroll
    for (int q = 0; q < PPR; q++) {
        if ((pr[q] >> 16) >= S_STEPS) {
            int p = pr[q] & 0xffff;
            float2 uA = *(const float2*)(s0 + p - RJ - 1);
            float2 uB = *(const float2*)(s0 + p - RJ + 1);
            float2 mA = *(const float2*)(s0 + p - 1);
            float2 mB = *(const float2*)(s0 + p + 1);
            float2 dA = *(const float2*)(s0 + p + RJ - 1);
            float2 dB = *(const float2*)(s0 + p + RJ + 1);
            float ax = Cc[q].x, ay = Cc[q].y;
            ax = fmaf(wp[q][0].x, dB.x, ax);  ay = fmaf(wp[q][0].y, dB.y, ay);
            ax = fmaf(wp[q][1].x, dA.y, ax);  ay = fmaf(wp[q][1].y, dB.x, ay);
            ax = fmaf(wp[q][2].x, dA.x, ax);  ay = fmaf(wp[q][2].y, dA.y, ay);
            ax = fmaf(wp[q][3].x, mB.x, ax);  ay = fmaf(wp[q][3].y, mB.y, ay);
            ax = fmaf(wp[q][4].x, mA.x, ax);  ay = fmaf(wp[q][4].y, mA.y, ay);
            ax = fmaf(wp[q][5].x, uB.x, ax);  ay = fmaf(wp[q][5].y, uB.y, ay);
            ax = fmaf(wp[q][6].x, uA.y, ax);  ay = fmaf(wp[q][6].y, uB.x, ay);
            ax = fmaf(wp[q][7].x, uA.x, ax);  ay = fmaf(wp[q][7].y, uA.y, ay);
            int ri = p / RJ, rj = p - ri * RJ;
            // maxring >= 8 guarantees ri in [8, RI-8); cols checked per px.
            int gbase = b * HW + (oi + ri) * Ww + (oj + rj);
            if (rj >= S_STEPS && rj < RJ - S_STEPS)
                dout[gbase]     = ax;
            if (rj + 1 >= S_STEPS && rj + 1 < RJ - S_STEPS)
                dout[gbase + 1] = ay;
        }
    }
}

extern "C" void kernel_launch(void* const* d_in, const int* in_sizes, int n_in,
                              void* d_out, int out_size, void* d_ws, size_t ws_size,
                              hipStream_t stream) {
    const float* guidance = (const float*)d_in[0];
    const float* blur     = (const float*)d_in[1];
    const float* sparse   = (const float*)d_in[2];
    float* out = (float*)d_out;

    char* ws = (char*)d_ws;
    float* bufA = (float*)ws;
    float* bufB = bufA + NPIX;

    // 24 steps = 3 launches x 8 fused steps
    mega<true ><<<GRID, BLOCK, 0, stream>>>(guidance, blur, sparse, nullptr, bufA);
    mega<false><<<GRID, BLOCK, 0, stream>>>(guidance, blur, sparse, bufA, bufB);
    mega<false><<<GRID, BLOCK, 0, stream>>>(guidance, blur, sparse, bufB, out);
}